// Round 1
// baseline (61.190 us; speedup 1.0000x reference)
//
#include <hip/hip_runtime.h>
#include <hip/hip_bf16.h>
#include <stdint.h>

// Only the LAST (seg_len=2048, dil=4) group survives in the reference (it
// overwrites `out`). So: 2 segments x 16 heads; seg 0 keys = n=0,4,..,4092
// (1024), seg 1 keys = n=2048,2052,..,4092 (512). Non-causal softmax attention
// with shared valid-key set per segment.

#define NH   16
#define HD   64
#define KMAX 1024

typedef __attribute__((ext_vector_type(8))) short s16x8;
typedef __attribute__((ext_vector_type(4))) float f32x4;

__device__ __forceinline__ ushort f2bf(float x) {
    union { float f; unsigned u; } c; c.f = x;
    unsigned u = c.u;
    u += 0x7fffu + ((u >> 16) & 1u);   // RTNE
    return (ushort)(u >> 16);
}

__device__ __forceinline__ void async_load16(const ushort* g, ushort* l) {
    __builtin_amdgcn_global_load_lds(
        (const __attribute__((address_space(1))) void*)g,
        (__attribute__((address_space(3))) void*)l, 16, 0, 0);
}

// ---------- prep: gather K/V at dilated positions -> bf16; V stored transposed
__global__ __launch_bounds__(256) void prep_kernel(
    const float* __restrict__ kin, const float* __restrict__ vin,
    ushort* __restrict__ Kb, ushort* __restrict__ Vt)
{
    int bid = blockIdx.x;
    int seg = bid >> 8;
    int h   = (bid >> 4) & 15;
    int ib  = bid & 15;
    int Kv  = seg ? 512 : 1024;
    int i0  = ib * 64;
    if (i0 >= Kv) return;

    int t  = threadIdx.x;
    int il = t >> 2;            // local key row 0..63
    int d0 = (t & 3) * 16;
    int i  = i0 + il;
    int pos = seg * 2048 + i * 4;   // dilation=4, always < 4096 for valid i

    const float* ks = kin + (size_t)pos * (NH*HD) + h * HD + d0;
    const float* vs = vin + (size_t)pos * (NH*HD) + h * HD + d0;

    __attribute__((aligned(16))) ushort kb[16];
    __attribute__((aligned(16))) ushort vb[16];
    #pragma unroll
    for (int j = 0; j < 4; ++j) {
        float4 a = ((const float4*)ks)[j];
        float4 b = ((const float4*)vs)[j];
        kb[j*4+0]=f2bf(a.x); kb[j*4+1]=f2bf(a.y); kb[j*4+2]=f2bf(a.z); kb[j*4+3]=f2bf(a.w);
        vb[j*4+0]=f2bf(b.x); vb[j*4+1]=f2bf(b.y); vb[j*4+2]=f2bf(b.z); vb[j*4+3]=f2bf(b.w);
    }
    size_t kdst = ((size_t)(seg*NH + h) * KMAX + i) * HD + d0;
    ((uint4*)(Kb + kdst))[0] = *(const uint4*)&kb[0];
    ((uint4*)(Kb + kdst))[1] = *(const uint4*)&kb[8];

    // transpose V tile via LDS (padded stride 72 to spread banks)
    __shared__ ushort vl[64 * 72];
    #pragma unroll
    for (int j = 0; j < 16; ++j) vl[il * 72 + d0 + j] = vb[j];
    __syncthreads();

    int d  = t >> 2;            // 0..63
    int ic = (t & 3) * 16;
    __attribute__((aligned(16))) ushort ob[16];
    #pragma unroll
    for (int j = 0; j < 16; ++j) ob[j] = vl[(ic + j) * 72 + d];
    size_t vdst = ((size_t)(seg*NH + h) * HD + d) * KMAX + i0 + ic;
    ((uint4*)(Vt + vdst))[0] = *(const uint4*)&ob[0];
    ((uint4*)(Vt + vdst))[1] = *(const uint4*)&ob[8];
}

// ---------- flash attention: 4 waves/block, 16 queries/wave, KBLK=64
__global__ __launch_bounds__(256) void attn_kernel(
    const float* __restrict__ qin, const ushort* __restrict__ Kb,
    const ushort* __restrict__ Vt, float* __restrict__ outp)
{
    int bid = blockIdx.x;
    int seg = bid >> 9;
    int h   = (bid >> 5) & 15;
    int qb  = bid & 31;
    int NT  = seg ? 8 : 16;     // key tiles of 64

    int tid  = threadIdx.x;
    int w    = tid >> 6;
    int lane = tid & 63;
    int r15  = lane & 15;
    int g    = lane >> 4;

    __shared__ __attribute__((aligned(16))) ushort k_lds[64*64];   // [key][d], xor-swizzled
    __shared__ __attribute__((aligned(16))) ushort v_lds[64*64];   // [d][key], xor-swizzled
    __shared__ __attribute__((aligned(16))) ushort p_lds[4*16*64]; // per-wave P buffer

    // Q A-fragments, scale 1/sqrt(64)=0.125 folded in (exact in bf16)
    s16x8 qa[2];
    {
        int qrow = seg*2048 + qb*64 + w*16 + r15;
        const float* qs = qin + (size_t)qrow * (NH*HD) + h*HD + g*8;
        #pragma unroll
        for (int f = 0; f < 2; ++f) {
            float4 a  = ((const float4*)(qs + f*32))[0];
            float4 b2 = ((const float4*)(qs + f*32))[1];
            s16x8 r;
            r[0]=(short)f2bf(a.x*0.125f);  r[1]=(short)f2bf(a.y*0.125f);
            r[2]=(short)f2bf(a.z*0.125f);  r[3]=(short)f2bf(a.w*0.125f);
            r[4]=(short)f2bf(b2.x*0.125f); r[5]=(short)f2bf(b2.y*0.125f);
            r[6]=(short)f2bf(b2.z*0.125f); r[7]=(short)f2bf(b2.w*0.125f);
            qa[f] = r;
        }
    }

    const ushort* KbH = Kb + (size_t)(seg*NH + h) * KMAX * HD;
    const ushort* VtH = Vt + (size_t)(seg*NH + h) * HD * KMAX;

    f32x4 O[4] = {{0,0,0,0},{0,0,0,0},{0,0,0,0},{0,0,0,0}};
    float m_r[4] = {-3e38f,-3e38f,-3e38f,-3e38f};
    float l_r[4] = {0.f,0.f,0.f,0.f};

    ushort* pw = p_lds + w * (16*64);

    for (int kt = 0; kt < NT; ++kt) {
        __syncthreads();   // previous tile fully consumed before overwrite
        {
            // stage K (chunks 0..7) and V^T (chunks 8..15); 1KB per chunk.
            // LDS dest is linear (lane*16); global source is pre-inverse-swizzled
            // so that a swizzled read (chunk ^ (row&7)) retrieves the data.
            int sub = lane >> 3;            // 0..7 -> row within chunk
            int csw = (lane & 7) ^ sub;     // source 16B-chunk (inverse swizzle)
            #pragma unroll
            for (int cc = 0; cc < 4; ++cc) {
                int c  = w*4 + cc;
                int cl = c & 7;
                int rowl = cl*8 + sub;      // 0..63
                if (c < 8) {
                    const ushort* gsrc = KbH + ((size_t)(kt*64 + rowl)) * HD + csw*8;
                    async_load16(gsrc, k_lds + c*512);
                } else {
                    const ushort* gsrc = VtH + (size_t)rowl * KMAX + kt*64 + csw*8;
                    async_load16(gsrc, v_lds + (c-8)*512);
                }
            }
        }
        __syncthreads();   // drains vmcnt -> staged data visible

        // ---- QK^T: S[t] = 16q x 16k tile (D=64 -> 2 MFMAs)
        f32x4 S[4];
        #pragma unroll
        for (int t = 0; t < 4; ++t) {
            int row = t*16 + r15;           // key row; row&7 == r15&7
            s16x8 b0 = *(const s16x8*)(k_lds + row*64 + ((g     ^ (r15&7))*8));
            s16x8 b1 = *(const s16x8*)(k_lds + row*64 + (((g+4) ^ (r15&7))*8));
            f32x4 z = {0.f,0.f,0.f,0.f};
            z    = __builtin_amdgcn_mfma_f32_16x16x32_bf16(qa[0], b0, z, 0,0,0);
            S[t] = __builtin_amdgcn_mfma_f32_16x16x32_bf16(qa[1], b1, z, 0,0,0);
        }

        // ---- online softmax (rows = (g*4+r), cols spread over lane&15 + 4 tiles)
        float rm[4];
        #pragma unroll
        for (int r = 0; r < 4; ++r)
            rm[r] = fmaxf(fmaxf(S[0][r], S[1][r]), fmaxf(S[2][r], S[3][r]));
        #pragma unroll
        for (int off = 1; off < 16; off <<= 1) {
            #pragma unroll
            for (int r = 0; r < 4; ++r) rm[r] = fmaxf(rm[r], __shfl_xor(rm[r], off));
        }
        float alpha[4], rs[4];
        #pragma unroll
        for (int r = 0; r < 4; ++r) {
            float mn = fmaxf(m_r[r], rm[r]);
            alpha[r] = __expf(m_r[r] - mn);
            m_r[r] = mn;
            rs[r] = 0.f;
        }
        ushort pb[4][4];
        #pragma unroll
        for (int t = 0; t < 4; ++t) {
            #pragma unroll
            for (int r = 0; r < 4; ++r) {
                float p = __expf(S[t][r] - m_r[r]);
                rs[r] += p;
                pb[t][r] = f2bf(p);
            }
        }
        #pragma unroll
        for (int off = 1; off < 16; off <<= 1) {
            #pragma unroll
            for (int r = 0; r < 4; ++r) rs[r] += __shfl_xor(rs[r], off);
        }
        #pragma unroll
        for (int r = 0; r < 4; ++r) l_r[r] = l_r[r]*alpha[r] + rs[r];
        #pragma unroll
        for (int dt = 0; dt < 4; ++dt) {
            f32x4 o = O[dt];
            o[0]*=alpha[0]; o[1]*=alpha[1]; o[2]*=alpha[2]; o[3]*=alpha[3];
            O[dt] = o;
        }

        // ---- P (C-layout) -> wave-private LDS (A-layout, swizzled)
        #pragma unroll
        for (int t = 0; t < 4; ++t) {
            #pragma unroll
            for (int r = 0; r < 4; ++r) {
                int row = g*4 + r;
                int col = r15 + 16*t;
                int off = row*64 + (((col>>3) ^ (row&7))*8) + (col&7);
                pw[off] = pb[t][r];
            }
        }
        // A-fragments: 8 contiguous keys per lane group
        s16x8 pa0 = *(const s16x8*)(pw + r15*64 + ((g     ^ (r15&7))*8));
        s16x8 pa1 = *(const s16x8*)(pw + r15*64 + (((g+4) ^ (r15&7))*8));

        // ---- PV: O[dt] += P * V  (V^T rows are d, contiguous keys)
        #pragma unroll
        for (int dt = 0; dt < 4; ++dt) {
            int row = dt*16 + r15;          // d row; row&7 == r15&7
            s16x8 vb0 = *(const s16x8*)(v_lds + row*64 + ((g     ^ (r15&7))*8));
            s16x8 vb1 = *(const s16x8*)(v_lds + row*64 + (((g+4) ^ (r15&7))*8));
            O[dt] = __builtin_amdgcn_mfma_f32_16x16x32_bf16(pa0, vb0, O[dt], 0,0,0);
            O[dt] = __builtin_amdgcn_mfma_f32_16x16x32_bf16(pa1, vb1, O[dt], 0,0,0);
        }
    }

    // ---- epilogue: normalize and store fp32
    float inv[4];
    #pragma unroll
    for (int r = 0; r < 4; ++r) inv[r] = 1.0f / l_r[r];
    size_t obase = (size_t)(seg*2048 + qb*64 + w*16) * (NH*HD) + h*HD;
    #pragma unroll
    for (int dt = 0; dt < 4; ++dt) {
        #pragma unroll
        for (int r = 0; r < 4; ++r)
            outp[obase + (size_t)(g*4 + r) * (NH*HD) + dt*16 + r15] = O[dt][r] * inv[r];
    }
}

extern "C" void kernel_launch(void* const* d_in, const int* in_sizes, int n_in,
                              void* d_out, int out_size, void* d_ws, size_t ws_size,
                              hipStream_t stream) {
    const float* q = (const float*)d_in[0];
    const float* k = (const float*)d_in[1];
    const float* v = (const float*)d_in[2];
    float* out = (float*)d_out;

    ushort* Kb = (ushort*)d_ws;                          // [2][16][1024][64] bf16 = 4 MB
    ushort* Vt = Kb + (size_t)2 * NH * KMAX * HD;        // [2][16][64][1024] bf16 = 4 MB

    prep_kernel<<<512, 256, 0, stream>>>(k, v, Kb, Vt);
    attn_kernel<<<1024, 256, 0, stream>>>(q, Kb, Vt, out);
}

// Round 2
// 47.775 us; speedup vs baseline: 1.2808x; 1.2808x over previous
//
#include <hip/hip_runtime.h>
#include <hip/hip_bf16.h>
#include <stdint.h>

// Only the LAST (seg_len=2048, dil=4) group survives in the reference.
// 2 segments x 16 heads; seg0 keys n=0,4,..,4092 (1024), seg1 keys
// n=2048,..,4092 (512). Non-causal attention, shared valid-key set.

#define NH   16
#define HD   64
#define KMAX 1024

typedef __attribute__((ext_vector_type(8))) short s16x8;
typedef __attribute__((ext_vector_type(4))) short s16x4;
typedef __attribute__((ext_vector_type(4))) float f32x4;

__device__ __forceinline__ ushort f2bf(float x) {
    union { float f; unsigned u; } c; c.f = x;
    unsigned u = c.u;
    u += 0x7fffu + ((u >> 16) & 1u);   // RTNE
    return (ushort)(u >> 16);
}

__device__ __forceinline__ void async_load16(const ushort* g, ushort* l) {
    __builtin_amdgcn_global_load_lds(
        (const __attribute__((address_space(1))) void*)g,
        (__attribute__((address_space(3))) void*)l, 16, 0, 0);
}

// ---------- prep: gather K/V at dilated positions -> bf16; V stored transposed
__global__ __launch_bounds__(256) void prep_kernel(
    const float* __restrict__ kin, const float* __restrict__ vin,
    ushort* __restrict__ Kb, ushort* __restrict__ Vt)
{
    int bid = blockIdx.x;
    int seg = bid >> 8;
    int h   = (bid >> 4) & 15;
    int ib  = bid & 15;
    int Kv  = seg ? 512 : 1024;
    int i0  = ib * 64;
    if (i0 >= Kv) return;

    int t  = threadIdx.x;
    int il = t >> 2;            // local key row 0..63
    int d0 = (t & 3) * 16;
    int i  = i0 + il;
    int pos = seg * 2048 + i * 4;

    const float* ks = kin + (size_t)pos * (NH*HD) + h * HD + d0;
    const float* vs = vin + (size_t)pos * (NH*HD) + h * HD + d0;

    __attribute__((aligned(16))) ushort kb[16];
    __attribute__((aligned(16))) ushort vb[16];
    #pragma unroll
    for (int j = 0; j < 4; ++j) {
        float4 a = ((const float4*)ks)[j];
        float4 b = ((const float4*)vs)[j];
        kb[j*4+0]=f2bf(a.x); kb[j*4+1]=f2bf(a.y); kb[j*4+2]=f2bf(a.z); kb[j*4+3]=f2bf(a.w);
        vb[j*4+0]=f2bf(b.x); vb[j*4+1]=f2bf(b.y); vb[j*4+2]=f2bf(b.z); vb[j*4+3]=f2bf(b.w);
    }
    size_t kdst = ((size_t)(seg*NH + h) * KMAX + i) * HD + d0;
    ((uint4*)(Kb + kdst))[0] = *(const uint4*)&kb[0];
    ((uint4*)(Kb + kdst))[1] = *(const uint4*)&kb[8];

    __shared__ ushort vl[64 * 72];
    #pragma unroll
    for (int j = 0; j < 16; ++j) vl[il * 72 + d0 + j] = vb[j];
    __syncthreads();

    int d  = t >> 2;
    int ic = (t & 3) * 16;
    __attribute__((aligned(16))) ushort ob[16];
    #pragma unroll
    for (int j = 0; j < 16; ++j) ob[j] = vl[(ic + j) * 72 + d];
    size_t vdst = ((size_t)(seg*NH + h) * HD + d) * KMAX + i0 + ic;
    ((uint4*)(Vt + vdst))[0] = *(const uint4*)&ob[0];
    ((uint4*)(Vt + vdst))[1] = *(const uint4*)&ob[8];
}

// ---------- flash attention: swapped-operand MFMA, in-register softmax,
// double-buffered LDS staging (one barrier per key tile).
__global__ __launch_bounds__(256, 4) void attn_kernel(
    const float* __restrict__ qin, const ushort* __restrict__ Kb,
    const ushort* __restrict__ Vt, float* __restrict__ outp)
{
    int bid = blockIdx.x;
    int sh  = bid & 31;          // low bits -> same (seg,h) clusters on one XCD
    int qb  = bid >> 5;
    int seg = sh >> 4;
    int h   = sh & 15;
    int NT  = seg ? 8 : 16;      // key tiles of 64

    int tid  = threadIdx.x;
    int w    = tid >> 6;
    int lane = tid & 63;
    int r15  = lane & 15;
    int g    = lane >> 4;
    int rsw  = r15 & 7;

    // [buf][K=0/V=1][64 rows x 64 elems], rows 128B, 16B-chunk XOR swizzle
    __shared__ __attribute__((aligned(16))) ushort smem[2][2][64*64];

    // ---- Q B-fragments (scale 1/8 exact in bf16): lane holds Q[q=r15][d=g*8+j(+32)]
    s16x8 qa0, qa1;
    int qrow = seg*2048 + qb*64 + w*16 + r15;
    {
        const float* qs = qin + (size_t)qrow * (NH*HD) + h*HD + g*8;
        float4 a = ((const float4*)qs)[0];
        float4 b = ((const float4*)qs)[1];
        qa0[0]=(short)f2bf(a.x*0.125f); qa0[1]=(short)f2bf(a.y*0.125f);
        qa0[2]=(short)f2bf(a.z*0.125f); qa0[3]=(short)f2bf(a.w*0.125f);
        qa0[4]=(short)f2bf(b.x*0.125f); qa0[5]=(short)f2bf(b.y*0.125f);
        qa0[6]=(short)f2bf(b.z*0.125f); qa0[7]=(short)f2bf(b.w*0.125f);
        const float* qs1 = qs + 32;
        float4 c = ((const float4*)qs1)[0];
        float4 d = ((const float4*)qs1)[1];
        qa1[0]=(short)f2bf(c.x*0.125f); qa1[1]=(short)f2bf(c.y*0.125f);
        qa1[2]=(short)f2bf(c.z*0.125f); qa1[3]=(short)f2bf(c.w*0.125f);
        qa1[4]=(short)f2bf(d.x*0.125f); qa1[5]=(short)f2bf(d.y*0.125f);
        qa1[6]=(short)f2bf(d.z*0.125f); qa1[7]=(short)f2bf(d.w*0.125f);
    }

    // ---- staging setup: waves 0-1 stage K, waves 2-3 stage V^T.
    const ushort* KbH = Kb + (size_t)(seg*NH + h) * KMAX * HD;
    const ushort* VtH = Vt + (size_t)(seg*NH + h) * HD * KMAX;
    int sub = lane >> 3;
    int csw = (lane & 7) ^ sub;          // inverse-swizzled source 16B-chunk
    bool isK = (w < 2);
    int kvsel = isK ? 0 : 1;
    size_t stride = isK ? (size_t)(64*HD) : (size_t)64;  // elements per tile step
    const ushort* gsrc[4];
    ushort* ld0[4];
    ushort* ld1[4];
    {
        int clb = (w & 1) * 4;
        #pragma unroll
        for (int cc = 0; cc < 4; ++cc) {
            int cl   = clb + cc;         // chunk 0..7 within K or V half
            int rowl = cl*8 + sub;       // row 0..63
            gsrc[cc] = isK ? (KbH + (size_t)rowl*HD   + csw*8)
                           : (VtH + (size_t)rowl*KMAX + csw*8);
            ld0[cc] = &smem[0][kvsel][cl*512];
            ld1[cc] = &smem[1][kvsel][cl*512];
        }
    }
    auto stage0 = [&](int kt) {
        size_t off = (size_t)kt * stride;
        #pragma unroll
        for (int cc = 0; cc < 4; ++cc) async_load16(gsrc[cc] + off, ld0[cc]);
    };
    auto stage1 = [&](int kt) {
        size_t off = (size_t)kt * stride;
        #pragma unroll
        for (int cc = 0; cc < 4; ++cc) async_load16(gsrc[cc] + off, ld1[cc]);
    };

    f32x4 O[4] = {{0,0,0,0},{0,0,0,0},{0,0,0,0},{0,0,0,0}};  // O^T[d=dt*16+4g+r][q=r15]
    float m = -3e38f, l = 0.f;

    auto compute = [&](const ushort* kbuf, const ushort* vbuf) {
        // QK^T swapped: S^T[key][q]; lane holds S[q=r15][k=16t+4g+r]
        f32x4 st[4];
        #pragma unroll
        for (int t = 0; t < 4; ++t) {
            const ushort* kr = kbuf + (t*16 + r15) * HD;
            s16x8 a0 = *(const s16x8*)(kr + (( g      ^ rsw) << 3));
            s16x8 a1 = *(const s16x8*)(kr + (((g + 4) ^ rsw) << 3));
            f32x4 z = {0.f,0.f,0.f,0.f};
            z     = __builtin_amdgcn_mfma_f32_16x16x32_bf16(a0, qa0, z, 0,0,0);
            st[t] = __builtin_amdgcn_mfma_f32_16x16x32_bf16(a1, qa1, z, 0,0,0);
        }
        // row max: in-lane tree + 2 cross-group shuffles
        float m0 = fmaxf(fmaxf(st[0][0], st[0][1]), fmaxf(st[0][2], st[0][3]));
        float m1 = fmaxf(fmaxf(st[1][0], st[1][1]), fmaxf(st[1][2], st[1][3]));
        float m2 = fmaxf(fmaxf(st[2][0], st[2][1]), fmaxf(st[2][2], st[2][3]));
        float m3 = fmaxf(fmaxf(st[3][0], st[3][1]), fmaxf(st[3][2], st[3][3]));
        float mt = fmaxf(fmaxf(m0, m1), fmaxf(m2, m3));
        mt = fmaxf(mt, __shfl_xor(mt, 16));
        mt = fmaxf(mt, __shfl_xor(mt, 32));
        // defer-max (T13): only rescale when some row grew > 8
        if (!__all(mt <= m + 8.0f)) {
            float mn = fmaxf(m, mt);
            float al = __expf(m - mn);
            m = mn;
            l *= al;
            #pragma unroll
            for (int dt = 0; dt < 4; ++dt) {
                f32x4 o = O[dt];
                o[0]*=al; o[1]*=al; o[2]*=al; o[3]*=al;
                O[dt] = o;
            }
        }
        // P = exp(S - m); lane layout == mfma16 B-fragment (k = 4g+j), no shuffles
        float rs = 0.f;
        s16x4 pf[4];
        #pragma unroll
        for (int t = 0; t < 4; ++t) {
            float p0 = __expf(st[t][0] - m);
            float p1 = __expf(st[t][1] - m);
            float p2 = __expf(st[t][2] - m);
            float p3 = __expf(st[t][3] - m);
            rs += (p0 + p1) + (p2 + p3);
            s16x4 pv;
            pv[0]=(short)f2bf(p0); pv[1]=(short)f2bf(p1);
            pv[2]=(short)f2bf(p2); pv[3]=(short)f2bf(p3);
            pf[t] = pv;
        }
        rs += __shfl_xor(rs, 16);
        rs += __shfl_xor(rs, 32);
        l += rs;
        // PV swapped: O^T += V^T * P^T via 16x16x16 bf16 MFMA
        #pragma unroll
        for (int dt = 0; dt < 4; ++dt) {
            const ushort* vr = vbuf + (dt*16 + r15) * HD;
            #pragma unroll
            for (int t = 0; t < 4; ++t) {
                int c = 2*t + (g >> 1);
                s16x4 vf = *(const s16x4*)(vr + ((c ^ rsw) << 3) + 4*(g & 1));
                O[dt] = __builtin_amdgcn_mfma_f32_16x16x16bf16_1k(vf, pf[t], O[dt], 0,0,0);
            }
        }
    };

    // ---- pipeline: stage(t+1) issued before compute(t); one barrier per tile
    stage0(0);
    __syncthreads();
    int kt = 0;
    while (true) {
        if (kt + 1 < NT) stage1(kt + 1);
        compute(&smem[0][0][0], &smem[0][1][0]);
        __syncthreads();
        ++kt; if (kt >= NT) break;
        if (kt + 1 < NT) stage0(kt + 1);
        compute(&smem[1][0][0], &smem[1][1][0]);
        __syncthreads();
        ++kt; if (kt >= NT) break;
    }

    // ---- epilogue: O^T column q=r15 -> out[q][h][d], float4 per d-subtile
    float invl = 1.0f / l;
    float* ob = outp + (size_t)qrow * (NH*HD) + h*HD + g*4;
    #pragma unroll
    for (int dt = 0; dt < 4; ++dt) {
        float4 o4 = { O[dt][0]*invl, O[dt][1]*invl, O[dt][2]*invl, O[dt][3]*invl };
        *(float4*)(ob + dt*16) = o4;
    }
}

extern "C" void kernel_launch(void* const* d_in, const int* in_sizes, int n_in,
                              void* d_out, int out_size, void* d_ws, size_t ws_size,
                              hipStream_t stream) {
    const float* q = (const float*)d_in[0];
    const float* k = (const float*)d_in[1];
    const float* v = (const float*)d_in[2];
    float* out = (float*)d_out;

    ushort* Kb = (ushort*)d_ws;                          // [2][16][1024][64] bf16
    ushort* Vt = Kb + (size_t)2 * NH * KMAX * HD;        // [2][16][64][1024] bf16

    prep_kernel<<<512, 256, 0, stream>>>(k, v, Kb, Vt);
    attn_kernel<<<1024, 256, 0, stream>>>(q, Kb, Vt, out);
}